// Round 2
// baseline (7701.170 us; speedup 1.0000x reference)
//
#include <hip/hip_runtime.h>
#include <hip/hip_bf16.h>

#define Bb    128
#define Ss    256
#define Ff    4
#define Vv    1024
#define Ee    512
#define Hh    1024
#define FourH 4096
#define Mrows (Bb * Ss)
#define NBLK  192      // 64 layer-0 WGs + 128 layer-1 WGs
#define NGRP  8
#define GSZ   (NBLK / NGRP)   // 24

typedef _Float16 f16;
typedef __attribute__((ext_vector_type(8))) _Float16 half8;
typedef __attribute__((ext_vector_type(4))) float f32x4;

// ---------------------------------------------------------------------------
__global__ void cvt_f16_kernel(const float* __restrict__ s, f16* __restrict__ d, int n) {
    int i = blockIdx.x * blockDim.x + threadIdx.x;
    int stride = gridDim.x * blockDim.x;
    for (; i < n; i += stride) d[i] = (f16)s[i];
}

__global__ void bias_combine_kernel(const float* __restrict__ a, const float* __restrict__ b,
                                    const float* __restrict__ c, const float* __restrict__ d,
                                    float* __restrict__ o0, float* __restrict__ o1) {
    int i = blockIdx.x * blockDim.x + threadIdx.x;
    if (i < FourH) o0[i] = a[i] + b[i];
    else if (i < 2 * FourH) { int j = i - FourH; o1[j] = c[j] + d[j]; }
}

// Embedding: sum over F tables -> f16 [S, B, E] (time-major)
__global__ void emb_kernel(const int* __restrict__ x, const float* __restrict__ emb,
                           f16* __restrict__ out) {
    int r = blockIdx.x;
    int t = threadIdx.x;
    int b = r / Ss, s = r % Ss;
    const int* xr = x + (size_t)r * Ff;
    const float* e0 = emb + (size_t)xr[0] * Ee;
    const float* e1 = emb + (size_t)(Vv + xr[1]) * Ee;
    const float* e2 = emb + (size_t)(2 * Vv + xr[2]) * Ee;
    const float* e3 = emb + (size_t)(3 * Vv + xr[3]) * Ee;
    f16* orow = out + (size_t)(s * Bb + b) * Ee;
    for (int e = t; e < Ee; e += 256) orow[e] = (f16)(e0[e] + e1[e] + e2[e] + e3[e]);
}

// ---------------------------------------------------------------------------
// C[M,N] = A[M,K] @ B[N,K]^T + bias[N]  (f16 in, f16 out, fp32 accum)
#define BM 128
#define BN 128
#define BK 32
#define LDP 40

__global__ __launch_bounds__(256) void gemm_bt_kernel(
    const f16* __restrict__ A, const f16* __restrict__ Bw,
    const float* __restrict__ bias, f16* __restrict__ C,
    int M, int N, int K)
{
    __shared__ f16 As[BM * LDP];
    __shared__ f16 Bs[BN * LDP];
    int tid  = threadIdx.x;
    int n0   = blockIdx.x * BN;
    int m0   = blockIdx.y * BM;
    int w    = tid >> 6, lane = tid & 63;
    int wm   = (w >> 1) * 64, wn = (w & 1) * 64;
    int lrow = lane & 15, koff = lane >> 4;

    f32x4 acc[4][4] = {};

    for (int kb = 0; kb < K; kb += BK) {
        __syncthreads();
        #pragma unroll
        for (int h = 0; h < 2; ++h) {
            int ch  = tid + h * 256;
            int row = ch >> 2;
            int cc  = (ch & 3) * 8;
            *reinterpret_cast<uint4*>(&As[row * LDP + cc]) =
                *reinterpret_cast<const uint4*>(A + (size_t)(m0 + row) * K + kb + cc);
            *reinterpret_cast<uint4*>(&Bs[row * LDP + cc]) =
                *reinterpret_cast<const uint4*>(Bw + (size_t)(n0 + row) * K + kb + cc);
        }
        __syncthreads();
        half8 af[4], bf[4];
        #pragma unroll
        for (int mt = 0; mt < 4; ++mt)
            af[mt] = *reinterpret_cast<const half8*>(&As[(wm + mt * 16 + lrow) * LDP + koff * 8]);
        #pragma unroll
        for (int nt = 0; nt < 4; ++nt)
            bf[nt] = *reinterpret_cast<const half8*>(&Bs[(wn + nt * 16 + lrow) * LDP + koff * 8]);
        #pragma unroll
        for (int mt = 0; mt < 4; ++mt)
            #pragma unroll
            for (int nt = 0; nt < 4; ++nt)
                acc[mt][nt] = __builtin_amdgcn_mfma_f32_16x16x32_f16(af[mt], bf[nt], acc[mt][nt], 0, 0, 0);
    }

    #pragma unroll
    for (int mt = 0; mt < 4; ++mt)
        #pragma unroll
        for (int nt = 0; nt < 4; ++nt) {
            int col = n0 + wn + nt * 16 + lrow;
            float bv = bias[col];
            #pragma unroll
            for (int r = 0; r < 4; ++r) {
                int rowg = m0 + wm + mt * 16 + koff * 4 + r;
                C[(size_t)rowg * N + col] = (f16)(acc[mt][nt][r] + bv);
            }
        }
}

// ---------------------------------------------------------------------------
__device__ __forceinline__ unsigned aload(unsigned* p) {
    return __hip_atomic_load(p, __ATOMIC_RELAXED, __HIP_MEMORY_SCOPE_AGENT);
}

// 2-level device-scope grid barrier. Monotonic generation counters.
__device__ __forceinline__ void grid_sync(unsigned* bar, int wg) {
    __syncthreads();
    if (threadIdx.x == 0) {
        const int g = wg & (NGRP - 1);
        unsigned* arr  = bar + g * 32;
        unsigned* rel  = bar + (8 + g) * 32;
        unsigned* root = bar + 16 * 32;
        unsigned* rrel = bar + 17 * 32;
        __threadfence();
        unsigned a   = atomicAdd(arr, 1u);
        unsigned gen = a / (unsigned)GSZ;
        if (a % (unsigned)GSZ == (unsigned)(GSZ - 1)) {       // group leader this gen
            unsigned r = atomicAdd(root, 1u);
            if (r % (unsigned)NGRP == (unsigned)(NGRP - 1)) {
                atomicAdd(rrel, 1u);                          // global release
            } else {
                while (aload(rrel) < gen + 1u) __builtin_amdgcn_s_sleep(2);
            }
            atomicAdd(rel, 1u);                               // group release
        }
        while (aload(rel) < gen + 1u) __builtin_amdgcn_s_sleep(2);
        __threadfence();
    }
    __syncthreads();
}

__device__ __forceinline__ float sigm(float v) { return 1.f / (1.f + __expf(-v)); }

// ---------------------------------------------------------------------------
// Persistent fused 2-layer LSTM scan. Iteration i: L0 computes step i (i<256),
// L1 computes step i-1 (i>=1). Weights held in registers for the whole launch.
//
// R2 structure: NO LDS staging for the A operand. Every wave's MFMA A-fragment
// is a row-strided 16B/lane global load (rows wm+mt*16+lrow, 32-f16 K-chunk),
// loaded straight into VGPRs, software-pipelined 3 slots / 2-chunks-ahead over
// 16 K-chunks. This removes all per-slice vmcnt(0)+__syncthreads lockstep;
// the only LDS use is the cross-wave partial-sum exchange (ep), so each
// iteration has exactly one __syncthreads plus the grid barrier.
// WGs 0..63: L0 (16 units, waves = m2 x gate-pair2 x Khalf2).
// WGs 64..191: L1 (8 units, K=2048=[wih1;whh1], waves = m2 x Kquarter4).
__global__ __launch_bounds__(512, 2) void scan_kernel(
    const f16* __restrict__ gx0,    // gates0 chunk base [nt][128][4096]
    int t_begin, int t_end,
    const f16* __restrict__ wih1, const f16* __restrict__ whh0,
    const f16* __restrict__ whh1, const float* __restrict__ bias1,
    f16* __restrict__ h0a, f16* __restrict__ h0b,
    f16* __restrict__ h1a, f16* __restrict__ h1b,
    float* __restrict__ c0, float* __restrict__ c1,
    float* __restrict__ out, unsigned* __restrict__ bar)
{
    __shared__ float ep[16 * 128 * 11];    // 90112 B; L0 uses 8*128*20 = 81920 B

    const int tid  = threadIdx.x;
    const int wg   = blockIdx.x;
    const int lane = tid & 63;
    const int w    = tid >> 6;
    const int lrow = lane & 15, koff = lane >> 4;

    if (wg < 64) {
        // ---------------- Layer 0: 16 units, waves = m(2) x gp(2) x kh(2)
        const int u0 = wg * 16;
        const int m  = w & 1, gp = (w >> 1) & 1, kh = w >> 2;
        const int wm = m * 64;

        half8 wreg[16][2];                 // [kc][nt]  (K = kh*512 + kc*32)
        #pragma unroll
        for (int t = 0; t < 16; ++t)
            #pragma unroll
            for (int nt = 0; nt < 2; ++nt)
                wreg[t][nt] = *(const half8*)(whh0
                    + (size_t)((gp * 2 + nt) * Hh + u0 + lrow) * Hh
                    + kh * 512 + t * 32 + koff * 8);

        float creg[4];
        #pragma unroll
        for (int q = 0; q < 4; ++q) {
            int p = tid + q * 512, row = p >> 4, uu = p & 15;
            creg[q] = c0[row * Hh + u0 + uu];
        }

        // per-lane byte offset of this lane's mt=0 A-fragment within h[.]
        const size_t abase = (size_t)(wm + lrow) * 2048 + (size_t)kh * 1024
                           + (size_t)koff * 16;

        for (int i = t_begin; i < t_end; ++i) {
            if (i < 256) {
                const f16* hp = (i & 1) ? h0a : h0b;   // h0[i-1]
                f16*       hw = (i & 1) ? h0b : h0a;   // h0[i]
                const f16* gx = gx0 + (size_t)(i - t_begin) * (Bb * FourH);

                // prefetch gate inputs (issued first; retire before A-chain waits)
                f16 gxr[4][4];
                #pragma unroll
                for (int q = 0; q < 4; ++q) {
                    int p = tid + q * 512, row = p >> 4, uu = p & 15;
                    const f16* gr = gx + (size_t)row * FourH + u0 + uu;
                    gxr[q][0] = gr[0];      gxr[q][1] = gr[Hh];
                    gxr[q][2] = gr[2 * Hh]; gxr[q][3] = gr[3 * Hh];
                }

                const char* pm0 = (const char*)hp + abase;
                const char* pm1 = pm0 + 32768;
                const char* pm2 = pm0 + 65536;
                const char* pm3 = pm0 + 98304;
                half8 ab[3][4];
                #define L0LD(s, kc) { \
                    ab[s][0] = *(const half8*)(pm0 + (kc) * 64); \
                    ab[s][1] = *(const half8*)(pm1 + (kc) * 64); \
                    ab[s][2] = *(const half8*)(pm2 + (kc) * 64); \
                    ab[s][3] = *(const half8*)(pm3 + (kc) * 64); }

                L0LD(0, 0)
                L0LD(1, 1)
                f32x4 acc[4][2] = {};
                #pragma unroll
                for (int kc = 0; kc < 16; ++kc) {
                    if (kc + 2 < 16) {
                        const int sn = (kc + 2) % 3;
                        L0LD(sn, kc + 2)
                    }
                    const int cs = kc % 3;
                    #pragma unroll
                    for (int mt = 0; mt < 4; ++mt) {
                        acc[mt][0] = __builtin_amdgcn_mfma_f32_16x16x32_f16(ab[cs][mt], wreg[kc][0], acc[mt][0], 0, 0, 0);
                        acc[mt][1] = __builtin_amdgcn_mfma_f32_16x16x32_f16(ab[cs][mt], wreg[kc][1], acc[mt][1], 0, 0, 0);
                    }
                }
                #undef L0LD

                // ep[((kh*4+g)*128+row)*20 + unit]
                #pragma unroll
                for (int mt = 0; mt < 4; ++mt)
                    #pragma unroll
                    for (int nt = 0; nt < 2; ++nt) {
                        int g = gp * 2 + nt;
                        int rowb = wm + mt * 16 + koff * 4;
                        #pragma unroll
                        for (int r = 0; r < 4; ++r)
                            ep[((kh * 4 + g) * 128 + rowb + r) * 20 + lrow] = acc[mt][nt][r];
                    }
                __syncthreads();
                #pragma unroll
                for (int q = 0; q < 4; ++q) {
                    int p = tid + q * 512, row = p >> 4, uu = p & 15;
                    float ipre = ep[(0 * 128 + row) * 20 + uu] + ep[(4 * 128 + row) * 20 + uu] + (float)gxr[q][0];
                    float fpre = ep[(1 * 128 + row) * 20 + uu] + ep[(5 * 128 + row) * 20 + uu] + (float)gxr[q][1];
                    float gpre = ep[(2 * 128 + row) * 20 + uu] + ep[(6 * 128 + row) * 20 + uu] + (float)gxr[q][2];
                    float opre = ep[(3 * 128 + row) * 20 + uu] + ep[(7 * 128 + row) * 20 + uu] + (float)gxr[q][3];
                    float cn = sigm(fpre) * creg[q] + sigm(ipre) * tanhf(gpre);
                    creg[q] = cn;
                    hw[row * Hh + u0 + uu] = (f16)(sigm(opre) * tanhf(cn));
                }
            }
            grid_sync(bar, wg);
        }
        #pragma unroll
        for (int q = 0; q < 4; ++q) {
            int p = tid + q * 512, row = p >> 4, uu = p & 15;
            c0[row * Hh + u0 + uu] = creg[q];
        }
    } else {
        // ---------------- Layer 1: 8 units, K=2048, waves = m(2) x kq(4)
        const int wgl = wg - 64;
        const int u0  = wgl * 8;
        const int m   = w & 1, kq = w >> 1;
        const int wm  = m * 64;
        const f16* wbase = (kq < 2) ? wih1 : whh1;

        half8 wreg[16][2];                 // [kc][nt]  (K = (kq&1)*512 + kc*32)
        #pragma unroll
        for (int t = 0; t < 16; ++t)
            #pragma unroll
            for (int nt = 0; nt < 2; ++nt) {
                int c = nt * 16 + lrow;                    // col in WG: gate=c>>3, unit=c&7
                wreg[t][nt] = *(const half8*)(wbase
                    + (size_t)((c >> 3) * Hh + u0 + (c & 7)) * Hh
                    + (kq & 1) * 512 + t * 32 + koff * 8);
            }

        float creg[2];
        #pragma unroll
        for (int q = 0; q < 2; ++q) {
            int p = tid + q * 512, row = p >> 3, uu = p & 7;
            creg[q] = c1[row * Hh + u0 + uu];
        }
        const int ub = tid & 7;            // unit (same for both q)
        float b0 = bias1[u0 + ub], b1 = bias1[Hh + u0 + ub],
              b2 = bias1[2 * Hh + u0 + ub], b3 = bias1[3 * Hh + u0 + ub];

        const size_t abase = (size_t)(wm + lrow) * 2048 + (size_t)(kq & 1) * 1024
                           + (size_t)koff * 16;

        for (int i = t_begin; i < t_end; ++i) {
            int t1 = i - 1;
            if (t1 >= 0) {
                const f16* a0 = (t1 & 1) ? h0b : h0a;  // h0[t1]
                const f16* a1 = (t1 & 1) ? h1a : h1b;  // h1[t1-1]
                f16*       hw = (t1 & 1) ? h1b : h1a;  // h1[t1]
                const char* src = (const char*)(kq < 2 ? a0 : a1) + abase;

                const char* pm0 = src;
                const char* pm1 = src + 32768;
                const char* pm2 = src + 65536;
                const char* pm3 = src + 98304;
                half8 ab[3][4];
                #define L1LD(s, kc) { \
                    ab[s][0] = *(const half8*)(pm0 + (kc) * 64); \
                    ab[s][1] = *(const half8*)(pm1 + (kc) * 64); \
                    ab[s][2] = *(const half8*)(pm2 + (kc) * 64); \
                    ab[s][3] = *(const half8*)(pm3 + (kc) * 64); }

                L1LD(0, 0)
                L1LD(1, 1)
                f32x4 acc[4][2] = {};
                #pragma unroll
                for (int kc = 0; kc < 16; ++kc) {
                    if (kc + 2 < 16) {
                        const int sn = (kc + 2) % 3;
                        L1LD(sn, kc + 2)
                    }
                    const int cs = kc % 3;
                    #pragma unroll
                    for (int mt = 0; mt < 4; ++mt) {
                        acc[mt][0] = __builtin_amdgcn_mfma_f32_16x16x32_f16(ab[cs][mt], wreg[kc][0], acc[mt][0], 0, 0, 0);
                        acc[mt][1] = __builtin_amdgcn_mfma_f32_16x16x32_f16(ab[cs][mt], wreg[kc][1], acc[mt][1], 0, 0, 0);
                    }
                }
                #undef L1LD

                // ep[((kq*4+g)*128+row)*11 + unit]
                #pragma unroll
                for (int mt = 0; mt < 4; ++mt)
                    #pragma unroll
                    for (int nt = 0; nt < 2; ++nt) {
                        int c = nt * 16 + lrow;
                        int g = c >> 3, uu = c & 7;
                        int rowb = wm + mt * 16 + koff * 4;
                        #pragma unroll
                        for (int r = 0; r < 4; ++r)
                            ep[((kq * 4 + g) * 128 + rowb + r) * 11 + uu] = acc[mt][nt][r];
                    }
                __syncthreads();
                #pragma unroll
                for (int q = 0; q < 2; ++q) {
                    int p = tid + q * 512, row = p >> 3, uu = p & 7;
                    float ipre = ep[(0 * 128 + row) * 11 + uu] + ep[(4 * 128 + row) * 11 + uu]
                               + ep[(8 * 128 + row) * 11 + uu] + ep[(12 * 128 + row) * 11 + uu] + b0;
                    float fpre = ep[(1 * 128 + row) * 11 + uu] + ep[(5 * 128 + row) * 11 + uu]
                               + ep[(9 * 128 + row) * 11 + uu] + ep[(13 * 128 + row) * 11 + uu] + b1;
                    float gpre = ep[(2 * 128 + row) * 11 + uu] + ep[(6 * 128 + row) * 11 + uu]
                               + ep[(10 * 128 + row) * 11 + uu] + ep[(14 * 128 + row) * 11 + uu] + b2;
                    float opre = ep[(3 * 128 + row) * 11 + uu] + ep[(7 * 128 + row) * 11 + uu]
                               + ep[(11 * 128 + row) * 11 + uu] + ep[(15 * 128 + row) * 11 + uu] + b3;
                    float cn = sigm(fpre) * creg[q] + sigm(ipre) * tanhf(gpre);
                    creg[q] = cn;
                    float hn = sigm(opre) * tanhf(cn);
                    hw[row * Hh + u0 + uu] = (f16)hn;
                    out[(size_t)row * (Ss * Hh) + (size_t)t1 * Hh + u0 + uu] = hn;
                }
            }
            grid_sync(bar, wg);
        }
        #pragma unroll
        for (int q = 0; q < 2; ++q) {
            int p = tid + q * 512, row = p >> 3, uu = p & 7;
            c1[row * Hh + u0 + uu] = creg[q];
        }
    }
}

// ---------------------------------------------------------------------------
extern "C" void kernel_launch(void* const* d_in, const int* in_sizes, int n_in,
                              void* d_out, int out_size, void* d_ws, size_t ws_size,
                              hipStream_t stream) {
    const int*   x      = (const int*)  d_in[0];
    const float* emb    = (const float*)d_in[1];
    const float* proj_w = (const float*)d_in[2];
    const float* proj_b = (const float*)d_in[3];
    const float* W_ih0  = (const float*)d_in[4];
    const float* W_hh0  = (const float*)d_in[5];
    const float* b_ih0  = (const float*)d_in[6];
    const float* b_hh0  = (const float*)d_in[7];
    const float* W_ih1  = (const float*)d_in[8];
    const float* W_hh1  = (const float*)d_in[9];
    const float* b_ih1  = (const float*)d_in[10];
    const float* b_hh1  = (const float*)d_in[11];
    float* out = (float*)d_out;

    char* ws = (char*)d_ws;
    f16* emb_sum = (f16*)(ws);                               // 32 MB [S,B,E]
    f16* x_in    = (f16*)(ws + 33554432ull);                 // 32 MB [S,B,E]
    f16* gates   = (f16*)(ws + 67108864ull);                 // 128 MB (128-step chunk)
    char* wp     = ws + 201326592ull;
    f16* pw_f   = (f16*)wp; wp += (size_t)Ee * Ee * 2;
    f16* wih0_f = (f16*)wp; wp += (size_t)FourH * Ee * 2;
    f16* whh0_f = (f16*)wp; wp += (size_t)FourH * Hh * 2;
    f16* wih1_f = (f16*)wp; wp += (size_t)FourH * Hh * 2;
    f16* whh1_f = (f16*)wp; wp += (size_t)FourH * Hh * 2;
    float* bias0 = (float*)wp; wp += FourH * 4;
    float* bias1 = (float*)wp; wp += FourH * 4;
    char* zbase = wp;
    f16*   h0a = (f16*)wp;   wp += (size_t)Bb * Hh * 2;
    f16*   h0b = (f16*)wp;   wp += (size_t)Bb * Hh * 2;
    f16*   h1a = (f16*)wp;   wp += (size_t)Bb * Hh * 2;
    f16*   h1b = (f16*)wp;   wp += (size_t)Bb * Hh * 2;
    float* c0  = (float*)wp; wp += (size_t)Bb * Hh * 4;
    float* c1  = (float*)wp; wp += (size_t)Bb * Hh * 4;
    unsigned* bar = (unsigned*)wp; wp += 4096;               // 2-level barrier counters
    size_t zbytes = (size_t)(wp - zbase);

    // Prologue: converts, biases, zero state+barrier
    cvt_f16_kernel<<<512, 256, 0, stream>>>(proj_w, pw_f,   Ee * Ee);
    cvt_f16_kernel<<<512, 256, 0, stream>>>(W_ih0,  wih0_f, FourH * Ee);
    cvt_f16_kernel<<<512, 256, 0, stream>>>(W_hh0,  whh0_f, FourH * Hh);
    cvt_f16_kernel<<<512, 256, 0, stream>>>(W_ih1,  wih1_f, FourH * Hh);
    cvt_f16_kernel<<<512, 256, 0, stream>>>(W_hh1,  whh1_f, FourH * Hh);
    bias_combine_kernel<<<32, 256, 0, stream>>>(b_ih0, b_hh0, b_ih1, b_hh1, bias0, bias1);
    hipMemsetAsync(zbase, 0, zbytes, stream);

    // Embedding + input projection (time-major)
    emb_kernel<<<Mrows, 256, 0, stream>>>(x, emb, emb_sum);
    gemm_bt_kernel<<<dim3(Ee / BN, Mrows / BM), 256, 0, stream>>>(
        emb_sum, pw_f, proj_b, x_in, Mrows, Ee, Ee);

    // Two half-sequence passes: gates0 GEMM chunk + cooperative scan
    const int CM = Mrows / 2;   // 16384 rows = 128 steps

    for (int half = 0; half < 2; ++half) {
        gemm_bt_kernel<<<dim3(FourH / BN, CM / BM), 256, 0, stream>>>(
            x_in + (size_t)half * CM * Ee, wih0_f, bias0, gates, CM, FourH, Ee);
        int tb = half * 128;
        int te = (half == 0) ? 128 : 257;   // second pass runs one extra L1-only iter
        const f16* gxp = gates;
        void* args[] = { (void*)&gxp, (void*)&tb, (void*)&te,
                         (void*)&wih1_f, (void*)&whh0_f, (void*)&whh1_f, (void*)&bias1,
                         (void*)&h0a, (void*)&h0b, (void*)&h1a, (void*)&h1b,
                         (void*)&c0, (void*)&c1, (void*)&out, (void*)&bar };
        hipLaunchCooperativeKernel((const void*)scan_kernel, dim3(NBLK), dim3(512),
                                   args, 0, stream);
    }
}

// Round 3
// 4679.790 us; speedup vs baseline: 1.6456x; 1.6456x over previous
//
#include <hip/hip_runtime.h>
#include <hip/hip_bf16.h>

#define Bb    128
#define Ss    256
#define Ff    4
#define Vv    1024
#define Ee    512
#define Hh    1024
#define FourH 4096
#define Mrows (Bb * Ss)
#define NBLK  192      // 64 layer-0 WGs + 128 layer-1 WGs
#define NGRP  8
#define GSZ   (NBLK / NGRP)   // 24

typedef _Float16 f16;
typedef __attribute__((ext_vector_type(8))) _Float16 half8;
typedef __attribute__((ext_vector_type(4))) float f32x4;

// ---------------------------------------------------------------------------
__global__ void cvt_f16_kernel(const float* __restrict__ s, f16* __restrict__ d, int n) {
    int i = blockIdx.x * blockDim.x + threadIdx.x;
    int stride = gridDim.x * blockDim.x;
    for (; i < n; i += stride) d[i] = (f16)s[i];
}

__global__ void bias_combine_kernel(const float* __restrict__ a, const float* __restrict__ b,
                                    const float* __restrict__ c, const float* __restrict__ d,
                                    float* __restrict__ o0, float* __restrict__ o1) {
    int i = blockIdx.x * blockDim.x + threadIdx.x;
    if (i < FourH) o0[i] = a[i] + b[i];
    else if (i < 2 * FourH) { int j = i - FourH; o1[j] = c[j] + d[j]; }
}

// Embedding: sum over F tables -> f16 [S, B, E] (time-major)
__global__ void emb_kernel(const int* __restrict__ x, const float* __restrict__ emb,
                           f16* __restrict__ out) {
    int r = blockIdx.x;
    int t = threadIdx.x;
    int b = r / Ss, s = r % Ss;
    const int* xr = x + (size_t)r * Ff;
    const float* e0 = emb + (size_t)xr[0] * Ee;
    const float* e1 = emb + (size_t)(Vv + xr[1]) * Ee;
    const float* e2 = emb + (size_t)(2 * Vv + xr[2]) * Ee;
    const float* e3 = emb + (size_t)(3 * Vv + xr[3]) * Ee;
    f16* orow = out + (size_t)(s * Bb + b) * Ee;
    for (int e = t; e < Ee; e += 256) orow[e] = (f16)(e0[e] + e1[e] + e2[e] + e3[e]);
}

// ---------------------------------------------------------------------------
// C[M,N] = A[M,K] @ B[N,K]^T + bias[N]  (f16 in, f16 out, fp32 accum)
#define BM 128
#define BN 128
#define BK 32
#define LDP 40

__global__ __launch_bounds__(256) void gemm_bt_kernel(
    const f16* __restrict__ A, const f16* __restrict__ Bw,
    const float* __restrict__ bias, f16* __restrict__ C,
    int M, int N, int K)
{
    __shared__ f16 As[BM * LDP];
    __shared__ f16 Bs[BN * LDP];
    int tid  = threadIdx.x;
    int n0   = blockIdx.x * BN;
    int m0   = blockIdx.y * BM;
    int w    = tid >> 6, lane = tid & 63;
    int wm   = (w >> 1) * 64, wn = (w & 1) * 64;
    int lrow = lane & 15, koff = lane >> 4;

    f32x4 acc[4][4] = {};

    for (int kb = 0; kb < K; kb += BK) {
        __syncthreads();
        #pragma unroll
        for (int h = 0; h < 2; ++h) {
            int ch  = tid + h * 256;
            int row = ch >> 2;
            int cc  = (ch & 3) * 8;
            *reinterpret_cast<uint4*>(&As[row * LDP + cc]) =
                *reinterpret_cast<const uint4*>(A + (size_t)(m0 + row) * K + kb + cc);
            *reinterpret_cast<uint4*>(&Bs[row * LDP + cc]) =
                *reinterpret_cast<const uint4*>(Bw + (size_t)(n0 + row) * K + kb + cc);
        }
        __syncthreads();
        half8 af[4], bf[4];
        #pragma unroll
        for (int mt = 0; mt < 4; ++mt)
            af[mt] = *reinterpret_cast<const half8*>(&As[(wm + mt * 16 + lrow) * LDP + koff * 8]);
        #pragma unroll
        for (int nt = 0; nt < 4; ++nt)
            bf[nt] = *reinterpret_cast<const half8*>(&Bs[(wn + nt * 16 + lrow) * LDP + koff * 8]);
        #pragma unroll
        for (int mt = 0; mt < 4; ++mt)
            #pragma unroll
            for (int nt = 0; nt < 4; ++nt)
                acc[mt][nt] = __builtin_amdgcn_mfma_f32_16x16x32_f16(af[mt], bf[nt], acc[mt][nt], 0, 0, 0);
    }

    #pragma unroll
    for (int mt = 0; mt < 4; ++mt)
        #pragma unroll
        for (int nt = 0; nt < 4; ++nt) {
            int col = n0 + wn + nt * 16 + lrow;
            float bv = bias[col];
            #pragma unroll
            for (int r = 0; r < 4; ++r) {
                int rowg = m0 + wm + mt * 16 + koff * 4 + r;
                C[(size_t)rowg * N + col] = (f16)(acc[mt][nt][r] + bv);
            }
        }
}

// ---------------------------------------------------------------------------
__device__ __forceinline__ void gload_lds16(const void* g, void* l) {
    __builtin_amdgcn_global_load_lds((const __attribute__((address_space(1))) void*)g,
                                     (__attribute__((address_space(3))) void*)l, 16, 0, 0);
}

__device__ __forceinline__ unsigned aload(unsigned* p) {
    return __hip_atomic_load(p, __ATOMIC_RELAXED, __HIP_MEMORY_SCOPE_AGENT);
}

// 2-level device-scope grid barrier. Monotonic generation counters.
__device__ __forceinline__ void grid_sync(unsigned* bar, int wg) {
    __syncthreads();
    if (threadIdx.x == 0) {
        const int g = wg & (NGRP - 1);
        unsigned* arr  = bar + g * 32;
        unsigned* rel  = bar + (8 + g) * 32;
        unsigned* root = bar + 16 * 32;
        unsigned* rrel = bar + 17 * 32;
        __threadfence();
        unsigned a   = atomicAdd(arr, 1u);
        unsigned gen = a / (unsigned)GSZ;
        if (a % (unsigned)GSZ == (unsigned)(GSZ - 1)) {       // group leader this gen
            unsigned r = atomicAdd(root, 1u);
            if (r % (unsigned)NGRP == (unsigned)(NGRP - 1)) {
                atomicAdd(rrel, 1u);                          // global release
            } else {
                while (aload(rrel) < gen + 1u) __builtin_amdgcn_s_sleep(2);
            }
            atomicAdd(rel, 1u);                               // group release
        }
        while (aload(rel) < gen + 1u) __builtin_amdgcn_s_sleep(2);
        __threadfence();
    }
    __syncthreads();
}

__device__ __forceinline__ float sigm(float v) { return 1.f / (1.f + __expf(-v)); }

// ---------------------------------------------------------------------------
// Persistent fused 2-layer LSTM scan. Iteration i: L0 computes step i (i<256),
// L1 computes step i-1 (i>=1). Weights held in registers for the whole launch.
//
// R3 structure: batch-row split across WGs (64 rows/WG) to cut per-CU staging.
//  L0: 64 WGs = rowg(2) x ug(32 units). N=128 gate-cols, K=1024.
//      Staging: single-shot 128 KB (64 rows x 2048 B) via global_load_lds,
//      one vmcnt(0) wait, then all compute. Waves = np(4) x kh(2).
//  L1: 128 WGs = rowg(2) x ug(64; 16 units). N=64 gate-cols, K=2048
//      (0..1023 = h0/wih1, 1024..2047 = h1/whh1). Staged as 4 K-slices of
//      64 KB, 2-buffer pipeline. Waves = np(2) x kq(4); wave kq's K-cols are
//      the 128-col blocks kq*128 + j*512 (one block per slice j -> all waves
//      busy every slice).
//  XOR-seg swizzle (16B segs within 128B groups, seg ^= row&7) applied to
//  the GLOBAL SOURCE address and the LDS READ address; LDS dest stays linear.
//  ep partial-sum buffers alias staging regions (barrier-guarded).
__global__ __launch_bounds__(512, 2) void scan_kernel(
    const f16* __restrict__ gx0,    // gates0 chunk base [nt][128][4096]
    int t_begin, int t_end,
    const f16* __restrict__ wih1, const f16* __restrict__ whh0,
    const f16* __restrict__ whh1, const float* __restrict__ bias1,
    f16* __restrict__ h0a, f16* __restrict__ h0b,
    f16* __restrict__ h1a, f16* __restrict__ h1b,
    float* __restrict__ c0, float* __restrict__ c1,
    float* __restrict__ out, unsigned* __restrict__ bar)
{
    __shared__ __align__(1024) char smem[131072];
    float* ep = (float*)smem;

    const int tid  = threadIdx.x;
    const int wg   = blockIdx.x;
    const int lane = tid & 63;
    const int w    = tid >> 6;
    const int lrow = lane & 15, koff = lane >> 4;
    const unsigned swz   = (unsigned)((lrow & 7) << 4);
    const unsigned e0s   = ((unsigned)(koff * 16)) ^ swz;         // (kc&1)==0
    const unsigned e1s   = ((unsigned)(64 + koff * 16)) ^ swz;    // (kc&1)==1
    const unsigned lane16 = (unsigned)(lane << 4);

    if (wg < 64) {
        // ---------------- Layer 0: rowg(2) x ug(32 units), waves np(4) x kh(2)
        const int rowg = wg >> 5, ug = wg & 31;
        const int np = w & 3, kh = w >> 2;
        const int u0 = ug * 32;
        const size_t growb = (size_t)rowg * 64;
        const int cw = np * 32 + lrow;         // + nt*16

        half8 wreg[16][2];
        #pragma unroll
        for (int kc = 0; kc < 16; ++kc)
            #pragma unroll
            for (int nt = 0; nt < 2; ++nt) {
                int c = cw + nt * 16;
                wreg[kc][nt] = *(const half8*)(whh0
                    + (size_t)((c >> 5) * Hh + u0 + (c & 31)) * Hh
                    + kh * 512 + kc * 32 + koff * 8);
            }

        float creg[4];
        #pragma unroll
        for (int q = 0; q < 4; ++q) {
            int p = tid + q * 512, row = p >> 5, uu = p & 31;
            creg[q] = c0[(growb + row) * Hh + u0 + uu];
        }

        for (int i = t_begin; i < t_end; ++i) {
            if (i < 256) {
                const f16* hp = (i & 1) ? h0a : h0b;   // h0[i-1]
                f16*       hw = (i & 1) ? h0b : h0a;   // h0[i]
                const f16* gx = gx0 + (size_t)(i - t_begin) * (Bb * FourH);
                const char* hb = (const char*)hp + growb * 2048;

                // single-shot stage: 64 rows x 2048 B (16 instr/wave)
                #pragma unroll
                for (int t = 0; t < 16; ++t) {
                    int row  = w * 8 + (t >> 1);
                    int half = t & 1;
                    gload_lds16(hb + (size_t)row * 2048 + half * 1024
                                   + (lane16 ^ ((unsigned)((row & 7) << 4))),
                                smem + row * 2048 + half * 1024);
                }
                // gate-input prefetch (retires with the same vmcnt wait)
                f16 gxr[4][4];
                #pragma unroll
                for (int q = 0; q < 4; ++q) {
                    int p = tid + q * 512, row = p >> 5, uu = p & 31;
                    const f16* gr = gx + (growb + row) * FourH + u0 + uu;
                    gxr[q][0] = gr[0];      gxr[q][1] = gr[Hh];
                    gxr[q][2] = gr[2 * Hh]; gxr[q][3] = gr[3 * Hh];
                }

                asm volatile("s_waitcnt vmcnt(0)" ::: "memory");
                __syncthreads();

                f32x4 acc[4][2] = {};
                #pragma unroll
                for (int kc = 0; kc < 16; ++kc) {
                    unsigned off = (unsigned)(kh * 1024 + (kc >> 1) * 128)
                                 + ((kc & 1) ? e1s : e0s);
                    half8 a[4];
                    #pragma unroll
                    for (int mt = 0; mt < 4; ++mt)
                        a[mt] = *(const half8*)(smem + (mt * 16 + lrow) * 2048 + off);
                    #pragma unroll
                    for (int mt = 0; mt < 4; ++mt) {
                        acc[mt][0] = __builtin_amdgcn_mfma_f32_16x16x32_f16(a[mt], wreg[kc][0], acc[mt][0], 0, 0, 0);
                        acc[mt][1] = __builtin_amdgcn_mfma_f32_16x16x32_f16(a[mt], wreg[kc][1], acc[mt][1], 0, 0, 0);
                    }
                }
                __syncthreads();           // staging reads done before ep overwrite
                // ep[kh][row][c] : [2][64][128]
                #pragma unroll
                for (int mt = 0; mt < 4; ++mt)
                    #pragma unroll
                    for (int nt = 0; nt < 2; ++nt) {
                        int c = cw + nt * 16;
                        int rowb = mt * 16 + koff * 4;
                        #pragma unroll
                        for (int r = 0; r < 4; ++r)
                            ep[(kh * 64 + rowb + r) * 128 + c] = acc[mt][nt][r];
                    }
                __syncthreads();
                #pragma unroll
                for (int q = 0; q < 4; ++q) {
                    int p = tid + q * 512, row = p >> 5, uu = p & 31;
                    float ipre = ep[row * 128 + uu]        + ep[(64 + row) * 128 + uu]        + (float)gxr[q][0];
                    float fpre = ep[row * 128 + 32 + uu]   + ep[(64 + row) * 128 + 32 + uu]   + (float)gxr[q][1];
                    float gpre = ep[row * 128 + 64 + uu]   + ep[(64 + row) * 128 + 64 + uu]   + (float)gxr[q][2];
                    float opre = ep[row * 128 + 96 + uu]   + ep[(64 + row) * 128 + 96 + uu]   + (float)gxr[q][3];
                    float cn = sigm(fpre) * creg[q] + sigm(ipre) * tanhf(gpre);
                    creg[q] = cn;
                    hw[(growb + row) * Hh + u0 + uu] = (f16)(sigm(opre) * tanhf(cn));
                }
            }
            grid_sync(bar, wg);
        }
        #pragma unroll
        for (int q = 0; q < 4; ++q) {
            int p = tid + q * 512, row = p >> 5, uu = p & 31;
            c0[(growb + row) * Hh + u0 + uu] = creg[q];
        }
    } else {
        // ---------------- Layer 1: rowg(2) x ug(64; 16 units), waves np(2) x kq(4)
        const int wgl = wg - 64;
        const int rowg = wgl >> 6, ug = wgl & 63;
        const int np = w & 1, kq = w >> 1;
        const int u0 = ug * 16;
        const size_t growb = (size_t)rowg * 64;
        const int cw = np * 32 + lrow;         // + nt*16

        half8 wreg[16][2];                     // [qk*4+cc][nt]
        #pragma unroll
        for (int qk = 0; qk < 4; ++qk) {
            const f16* wb = (qk < 2) ? wih1 : whh1;
            #pragma unroll
            for (int cc = 0; cc < 4; ++cc)
                #pragma unroll
                for (int nt = 0; nt < 2; ++nt) {
                    int c = cw + nt * 16;
                    wreg[qk * 4 + cc][nt] = *(const half8*)(wb
                        + (size_t)((c >> 4) * Hh + u0 + (c & 15)) * Hh
                        + kq * 128 + (qk & 1) * 512 + cc * 32 + koff * 8);
                }
        }

        float creg[2];
        #pragma unroll
        for (int q = 0; q < 2; ++q) {
            int p = tid + q * 512, row = p >> 4, uu = p & 15;
            creg[q] = c1[(growb + row) * Hh + u0 + uu];
        }
        const int ub = tid & 15;
        float b0 = bias1[u0 + ub], b1 = bias1[Hh + u0 + ub],
              b2 = bias1[2 * Hh + u0 + ub], b3 = bias1[3 * Hh + u0 + ub];

        for (int i = t_begin; i < t_end; ++i) {
            int t1 = i - 1;
            if (t1 >= 0) {
                const f16* a0 = (t1 & 1) ? h0b : h0a;  // h0[t1]
                const f16* a1 = (t1 & 1) ? h1a : h1b;  // h1[t1-1]
                f16*       hw = (t1 & 1) ? h1b : h1a;  // h1[t1]
                const char* s0 = (const char*)a0 + growb * 2048;
                const char* s1 = (const char*)a1 + growb * 2048;

                auto stage1 = [&](int jj, char* dst) {
                    const char* sp = (jj < 2) ? s0 : s1;
                    unsigned cb = ((unsigned)(jj & 1)) * 1024u;
                    #pragma unroll
                    for (int t = 0; t < 8; ++t) {
                        int row = w * 8 + t;
                        gload_lds16(sp + (size_t)row * 2048 + cb
                                       + (lane16 ^ ((unsigned)((row & 7) << 4))),
                                    dst + row * 1024);
                    }
                };

                stage1(0, smem);                        // slice 0 -> buf 0
                f32x4 acc[4][2] = {};
                int cur = 0;
                #pragma unroll
                for (int j = 0; j < 4; ++j) {
                    asm volatile("s_waitcnt vmcnt(0)" ::: "memory");
                    __syncthreads();
                    if (j < 3) stage1(j + 1, smem + (cur ^ 1) * 65536);
                    const char* rb = smem + cur * 65536;
                    #pragma unroll
                    for (int cc = 0; cc < 4; ++cc) {
                        unsigned off = (unsigned)(kq * 256 + (cc >> 1) * 128)
                                     + ((cc & 1) ? e1s : e0s);
                        half8 a[4];
                        #pragma unroll
                        for (int mt = 0; mt < 4; ++mt)
                            a[mt] = *(const half8*)(rb + (mt * 16 + lrow) * 1024 + off);
                        #pragma unroll
                        for (int mt = 0; mt < 4; ++mt) {
                            acc[mt][0] = __builtin_amdgcn_mfma_f32_16x16x32_f16(a[mt], wreg[j * 4 + cc][0], acc[mt][0], 0, 0, 0);
                            acc[mt][1] = __builtin_amdgcn_mfma_f32_16x16x32_f16(a[mt], wreg[j * 4 + cc][1], acc[mt][1], 0, 0, 0);
                        }
                    }
                    cur ^= 1;
                }
                // ep[kq][row][c] : [4][64][64] -> aliases buf0 (last read at j=2;
                // all waves are past j=3's barrier, so buf0 is free)
                #pragma unroll
                for (int mt = 0; mt < 4; ++mt)
                    #pragma unroll
                    for (int nt = 0; nt < 2; ++nt) {
                        int c = cw + nt * 16;
                        int rowb = mt * 16 + koff * 4;
                        #pragma unroll
                        for (int r = 0; r < 4; ++r)
                            ep[(kq * 64 + rowb + r) * 64 + c] = acc[mt][nt][r];
                    }
                __syncthreads();
                #pragma unroll
                for (int q = 0; q < 2; ++q) {
                    int p = tid + q * 512, row = p >> 4, uu = p & 15;
                    float ipre = ep[row * 64 + uu]        + ep[(64 + row) * 64 + uu]
                               + ep[(128 + row) * 64 + uu] + ep[(192 + row) * 64 + uu] + b0;
                    float fpre = ep[row * 64 + 16 + uu]   + ep[(64 + row) * 64 + 16 + uu]
                               + ep[(128 + row) * 64 + 16 + uu] + ep[(192 + row) * 64 + 16 + uu] + b1;
                    float gpre = ep[row * 64 + 32 + uu]   + ep[(64 + row) * 64 + 32 + uu]
                               + ep[(128 + row) * 64 + 32 + uu] + ep[(192 + row) * 64 + 32 + uu] + b2;
                    float opre = ep[row * 64 + 48 + uu]   + ep[(64 + row) * 64 + 48 + uu]
                               + ep[(128 + row) * 64 + 48 + uu] + ep[(192 + row) * 64 + 48 + uu] + b3;
                    float cn = sigm(fpre) * creg[q] + sigm(ipre) * tanhf(gpre);
                    creg[q] = cn;
                    float hn = sigm(opre) * tanhf(cn);
                    hw[(growb + row) * Hh + u0 + uu] = (f16)hn;
                    out[(growb + row) * (size_t)(Ss * Hh) + (size_t)t1 * Hh + u0 + uu] = hn;
                }
            }
            grid_sync(bar, wg);
        }
        #pragma unroll
        for (int q = 0; q < 2; ++q) {
            int p = tid + q * 512, row = p >> 4, uu = p & 15;
            c1[(growb + row) * Hh + u0 + uu] = creg[q];
        }
    }
}

// ---------------------------------------------------------------------------
extern "C" void kernel_launch(void* const* d_in, const int* in_sizes, int n_in,
                              void* d_out, int out_size, void* d_ws, size_t ws_size,
                              hipStream_t stream) {
    const int*   x      = (const int*)  d_in[0];
    const float* emb    = (const float*)d_in[1];
    const float* proj_w = (const float*)d_in[2];
    const float* proj_b = (const float*)d_in[3];
    const float* W_ih0  = (const float*)d_in[4];
    const float* W_hh0  = (const float*)d_in[5];
    const float* b_ih0  = (const float*)d_in[6];
    const float* b_hh0  = (const float*)d_in[7];
    const float* W_ih1  = (const float*)d_in[8];
    const float* W_hh1  = (const float*)d_in[9];
    const float* b_ih1  = (const float*)d_in[10];
    const float* b_hh1  = (const float*)d_in[11];
    float* out = (float*)d_out;

    char* ws = (char*)d_ws;
    f16* emb_sum = (f16*)(ws);                               // 32 MB [S,B,E]
    f16* x_in    = (f16*)(ws + 33554432ull);                 // 32 MB [S,B,E]
    f16* gates   = (f16*)(ws + 67108864ull);                 // 128 MB (128-step chunk)
    char* wp     = ws + 201326592ull;
    f16* pw_f   = (f16*)wp; wp += (size_t)Ee * Ee * 2;
    f16* wih0_f = (f16*)wp; wp += (size_t)FourH * Ee * 2;
    f16* whh0_f = (f16*)wp; wp += (size_t)FourH * Hh * 2;
    f16* wih1_f = (f16*)wp; wp += (size_t)FourH * Hh * 2;
    f16* whh1_f = (f16*)wp; wp += (size_t)FourH * Hh * 2;
    float* bias0 = (float*)wp; wp += FourH * 4;
    float* bias1 = (float*)wp; wp += FourH * 4;
    char* zbase = wp;
    f16*   h0a = (f16*)wp;   wp += (size_t)Bb * Hh * 2;
    f16*   h0b = (f16*)wp;   wp += (size_t)Bb * Hh * 2;
    f16*   h1a = (f16*)wp;   wp += (size_t)Bb * Hh * 2;
    f16*   h1b = (f16*)wp;   wp += (size_t)Bb * Hh * 2;
    float* c0  = (float*)wp; wp += (size_t)Bb * Hh * 4;
    float* c1  = (float*)wp; wp += (size_t)Bb * Hh * 4;
    unsigned* bar = (unsigned*)wp; wp += 4096;               // 2-level barrier counters
    size_t zbytes = (size_t)(wp - zbase);

    // Prologue: converts, biases, zero state+barrier
    cvt_f16_kernel<<<512, 256, 0, stream>>>(proj_w, pw_f,   Ee * Ee);
    cvt_f16_kernel<<<512, 256, 0, stream>>>(W_ih0,  wih0_f, FourH * Ee);
    cvt_f16_kernel<<<512, 256, 0, stream>>>(W_hh0,  whh0_f, FourH * Hh);
    cvt_f16_kernel<<<512, 256, 0, stream>>>(W_ih1,  wih1_f, FourH * Hh);
    cvt_f16_kernel<<<512, 256, 0, stream>>>(W_hh1,  whh1_f, FourH * Hh);
    bias_combine_kernel<<<32, 256, 0, stream>>>(b_ih0, b_hh0, b_ih1, b_hh1, bias0, bias1);
    hipMemsetAsync(zbase, 0, zbytes, stream);

    // Embedding + input projection (time-major)
    emb_kernel<<<Mrows, 256, 0, stream>>>(x, emb, emb_sum);
    gemm_bt_kernel<<<dim3(Ee / BN, Mrows / BM), 256, 0, stream>>>(
        emb_sum, pw_f, proj_b, x_in, Mrows, Ee, Ee);

    // Two half-sequence passes: gates0 GEMM chunk + cooperative scan
    const int CM = Mrows / 2;   // 16384 rows = 128 steps

    for (int half = 0; half < 2; ++half) {
        gemm_bt_kernel<<<dim3(FourH / BN, CM / BM), 256, 0, stream>>>(
            x_in + (size_t)half * CM * Ee, wih0_f, bias0, gates, CM, FourH, Ee);
        int tb = half * 128;
        int te = (half == 0) ? 128 : 257;   // second pass runs one extra L1-only iter
        const f16* gxp = gates;
        void* args[] = { (void*)&gxp, (void*)&tb, (void*)&te,
                         (void*)&wih1_f, (void*)&whh0_f, (void*)&whh1_f, (void*)&bias1,
                         (void*)&h0a, (void*)&h0b, (void*)&h1a, (void*)&h1b,
                         (void*)&c0, (void*)&c1, (void*)&out, (void*)&bar };
        hipLaunchCooperativeKernel((const void*)scan_kernel, dim3(NBLK), dim3(512),
                                   args, 0, stream);
    }
}